// Round 1
// baseline (301.997 us; speedup 1.0000x reference)
//
#include <hip/hip_runtime.h>

// Problem constants (from reference setup_inputs)
#define Bz 16      // batch
#define Tin 12     // T_IN
#define Ttot 24    // T_TOTAL
#define NN 5000    // nodes
#define Cc 4       // channels
#define KK 16      // neighbors
#define HH 4       // heads
#define OO 12      // T_TOTAL - T_IN (GEMM out dim)
#define TH 48      // Tin * HH (GEMM in dim)

__global__ __launch_bounds__(256, 4) void gnn_extrap_kernel(
    const float* __restrict__ x,      // (B,T,N,C)
    const float* __restrict__ dists,  // (N,K)
    const float* __restrict__ W,      // (48,12)
    const float* __restrict__ bias,   // (12,)
    const int*   __restrict__ nbrs,   // (N,K)
    float* __restrict__ out)          // (B,24,N,C)
{
    const int n   = blockIdx.x;
    const int tid = threadIdx.x;

    __shared__ float w_s[KK][HH];         // gaussian weights, per node
    __shared__ float feat_s[TH][Bz][Cc];  // [t*4+h][b][c] : 3072 floats (12 KB)
    __shared__ float W_s[TH][OO];         // 576 floats
    __shared__ float bias_s[OO];
    __shared__ int   nbr_s[KK];

    // ---- stage small tensors to LDS ----
    for (int i = tid; i < TH * OO; i += 256) ((float*)W_s)[i] = W[i];
    if (tid < OO) bias_s[tid] = bias[tid];
    if (tid < KK) nbr_s[tid] = nbrs[n * KK + tid];
    if (tid < KK * HH) {
        int k = tid >> 2, h = tid & 3;
        float d   = dists[n * KK + k];
        float lam = (float)(h + 1) * 0.25f;
        w_s[k][h] = expf(-(d * d) * lam * (1.0f / 36.0f));
    }
    __syncthreads();

    // ---- phase 1: gather + head-weighted aggregate; also the concat copy ----
    if (tid < Bz * Tin) {
        const int b = tid / Tin;
        const int t = tid - b * Tin;
        const float* xrow = x + (size_t)((b * Tin + t) * NN) * Cc;

        // concat: out[b, t, n, :] = x[b, t, n, :]
        float4 xself = *(const float4*)(xrow + (size_t)n * Cc);
        *(float4*)(out + ((size_t)(b * Ttot + t) * NN + n) * Cc) = xself;

        float agg[HH][Cc];
        #pragma unroll
        for (int h = 0; h < HH; h++)
            #pragma unroll
            for (int c = 0; c < Cc; c++) agg[h][c] = 0.0f;

        #pragma unroll
        for (int k = 0; k < KK; k++) {
            float4 xv = *(const float4*)(xrow + (size_t)nbr_s[k] * Cc);
            #pragma unroll
            for (int h = 0; h < HH; h++) {
                float wk = w_s[k][h];
                agg[h][0] += wk * xv.x;
                agg[h][1] += wk * xv.y;
                agg[h][2] += wk * xv.z;
                agg[h][3] += wk * xv.w;
            }
        }

        #pragma unroll
        for (int h = 0; h < HH; h++) {
            float4 v = make_float4(agg[h][0], agg[h][1], agg[h][2], agg[h][3]);
            *(float4*)(&feat_s[t * HH + h][b][0]) = v;
        }
    }
    __syncthreads();

    // ---- phase 2: (48 -> 12) GEMM + bias + ReLU, store y[b, 12+o, n, 0:4] ----
    if (tid < Bz * OO) {
        const int b = tid / OO;
        const int o = tid - b * OO;
        float acc0 = bias_s[o], acc1 = bias_s[o], acc2 = bias_s[o], acc3 = bias_s[o];
        #pragma unroll
        for (int th = 0; th < TH; th++) {
            float wv = W_s[th][o];
            float4 f = *(const float4*)(&feat_s[th][b][0]);
            acc0 += wv * f.x;
            acc1 += wv * f.y;
            acc2 += wv * f.z;
            acc3 += wv * f.w;
        }
        float4 yv = make_float4(fmaxf(acc0, 0.0f), fmaxf(acc1, 0.0f),
                                fmaxf(acc2, 0.0f), fmaxf(acc3, 0.0f));
        *(float4*)(out + ((size_t)(b * Ttot + Tin + o) * NN + n) * Cc) = yv;
    }
}

extern "C" void kernel_launch(void* const* d_in, const int* in_sizes, int n_in,
                              void* d_out, int out_size, void* d_ws, size_t ws_size,
                              hipStream_t stream) {
    const float* x     = (const float*)d_in[0];
    const float* dists = (const float*)d_in[1];
    const float* W     = (const float*)d_in[2];
    const float* bias  = (const float*)d_in[3];
    const int*   nbrs  = (const int*)d_in[4];
    float* out = (float*)d_out;

    hipLaunchKernelGGL(gnn_extrap_kernel, dim3(NN), dim3(256), 0, stream,
                       x, dists, W, bias, nbrs, out);
}

// Round 2
// 218.221 us; speedup vs baseline: 1.3839x; 1.3839x over previous
//
#include <hip/hip_runtime.h>

// Problem constants
#define Bz 16      // batch
#define Tin 12     // T_IN
#define Ttot 24    // T_TOTAL
#define NN 5000    // nodes
#define Cc 4       // channels
#define KK 16      // neighbors
#define HH 4       // heads
#define OO 12      // T_TOTAL - T_IN
#define TH 48      // Tin * HH
#define BT 192     // Bz * Tin

// ================= kernel 1: transpose x -> xT(N, BT) + concat copy =========
// x is (B,T,N,C) = (BT, N) float4 rows; xT is (N, BT) float4.
// Fuses out[b,t,n,:] = x[b,t,n,:] (it reads x anyway, coalesced).
#define K1_NB 64   // nodes per tile
#define K1_BT 24   // (b,t) pairs per tile

__global__ __launch_bounds__(256) void transpose_concat_kernel(
    const float4* __restrict__ x4,   // (BT, N)
    float4* __restrict__ xT4,        // (N, BT)
    float4* __restrict__ out4)       // (B*Ttot, N)
{
    __shared__ float4 tile[K1_BT][K1_NB + 1];   // +1 pad breaks bank stride
    const int n0  = blockIdx.x * K1_NB;
    const int bt0 = blockIdx.y * K1_BT;
    const int rem = min(K1_NB, NN - n0);
    const int tid = threadIdx.x;

    // load (coalesced along n) + concat copy
    #pragma unroll
    for (int r = 0; r < (K1_NB * K1_BT) / 256; r++) {
        int tau = r * 256 + tid;
        int j = tau / K1_NB;          // bt index in tile
        int i = tau % K1_NB;          // node index in tile (lane-consecutive)
        if (i < rem) {
            int bt = bt0 + j;
            float4 v = x4[(size_t)bt * NN + n0 + i];
            tile[j][i] = v;
            int b = bt / Tin, t = bt - b * Tin;
            out4[(size_t)(b * Ttot + t) * NN + n0 + i] = v;
        }
    }
    __syncthreads();

    // store xT (coalesced along bt: 384 B contiguous per node)
    #pragma unroll
    for (int r = 0; r < (K1_NB * K1_BT) / 256; r++) {
        int tau = r * 256 + tid;
        int i = tau / K1_BT;          // node
        int j = tau - i * K1_BT;      // bt (lane-consecutive)
        if (i < rem) {
            xT4[(size_t)(n0 + i) * BT + bt0 + j] = tile[j][i];
        }
    }
}

// ================= kernel 2: gather + aggregate + GEMM + ReLU ===============
#define NPB 4                 // nodes per block
#define FSB 49                // feat float4-stride per b   (Bz pad: 48+1)
#define FSN 785               // feat float4-stride per nl  (16*49+1)

__global__ __launch_bounds__(768, 6) void gnn_main_kernel(
    const float4* __restrict__ xT4,   // (N, BT)
    const float* __restrict__ dists,  // (N, K)
    const float* __restrict__ W,      // (48, 12)
    const float* __restrict__ bias,   // (12,)
    const int*   __restrict__ nbrs,   // (N, K)
    float4* __restrict__ out4)        // (B*Ttot, N)
{
    __shared__ float4 feat[NPB * FSN];        // ~50.2 KB, padded strides
    __shared__ float  w_s[NPB][KK][HH];
    __shared__ float  W_s[TH * OO];
    __shared__ float  bias_s[OO];
    __shared__ int    nbr_s[NPB][KK];

    const int n0  = blockIdx.x * NPB;
    const int tid = threadIdx.x;

    // ---- stage small tensors ----
    if (tid < TH * OO) W_s[tid] = W[tid];
    if (tid < OO) bias_s[tid] = bias[tid];
    if (tid < NPB * KK) {
        int nl = tid >> 4, k = tid & 15;
        nbr_s[nl][k] = nbrs[(n0 + nl) * KK + k];
    }
    if (tid >= 256 && tid < 256 + NPB * KK * HH) {
        int u = tid - 256;
        int nl = u >> 6, k = (u >> 2) & 15, h = u & 3;
        float d   = dists[(n0 + nl) * KK + k];
        float lam = (float)(h + 1) * 0.25f;
        w_s[nl][k][h] = expf(-(d * d) * lam * (1.0f / 36.0f));
    }
    __syncthreads();

    // ---- phase A: gather (contiguous 3 KB rows, 1 KB/wave) + aggregate ----
    {
        const int nl = tid / BT;          // wave-uniform (192 = 3 waves)
        const int bt = tid - nl * BT;     // lane-consecutive
        float4 a0 = {0,0,0,0}, a1 = {0,0,0,0}, a2 = {0,0,0,0}, a3 = {0,0,0,0};
        #pragma unroll
        for (int k = 0; k < KK; k++) {
            float4 xv = xT4[(size_t)nbr_s[nl][k] * BT + bt];
            float w0 = w_s[nl][k][0], w1 = w_s[nl][k][1];
            float w2 = w_s[nl][k][2], w3 = w_s[nl][k][3];
            a0.x += w0 * xv.x; a0.y += w0 * xv.y; a0.z += w0 * xv.z; a0.w += w0 * xv.w;
            a1.x += w1 * xv.x; a1.y += w1 * xv.y; a1.z += w1 * xv.z; a1.w += w1 * xv.w;
            a2.x += w2 * xv.x; a2.y += w2 * xv.y; a2.z += w2 * xv.z; a2.w += w2 * xv.w;
            a3.x += w3 * xv.x; a3.y += w3 * xv.y; a3.z += w3 * xv.z; a3.w += w3 * xv.w;
        }
        int b = bt / Tin, t = bt - b * Tin;
        int base = nl * FSN + b * FSB + t * HH;
        feat[base + 0] = a0;
        feat[base + 1] = a1;
        feat[base + 2] = a2;
        feat[base + 3] = a3;
    }
    __syncthreads();

    // ---- phase B: (48 -> 12) GEMM + bias + ReLU, 64 B contiguous stores ----
    {
        const int nl = tid & 3;           // lane-consecutive -> 64 B lines
        const int bo = tid >> 2;
        const int b  = bo / OO, o = bo - b * OO;
        float bz = bias_s[o];
        float4 acc = {bz, bz, bz, bz};
        const int fbase = nl * FSN + b * FSB;
        #pragma unroll
        for (int th = 0; th < TH; th++) {
            float  wv = W_s[th * OO + o];
            float4 f  = feat[fbase + th];
            acc.x += wv * f.x; acc.y += wv * f.y;
            acc.z += wv * f.z; acc.w += wv * f.w;
        }
        acc.x = fmaxf(acc.x, 0.0f); acc.y = fmaxf(acc.y, 0.0f);
        acc.z = fmaxf(acc.z, 0.0f); acc.w = fmaxf(acc.w, 0.0f);
        out4[(size_t)(b * Ttot + Tin + o) * NN + n0 + nl] = acc;
    }
}

extern "C" void kernel_launch(void* const* d_in, const int* in_sizes, int n_in,
                              void* d_out, int out_size, void* d_ws, size_t ws_size,
                              hipStream_t stream) {
    const float* x     = (const float*)d_in[0];
    const float* dists = (const float*)d_in[1];
    const float* W     = (const float*)d_in[2];
    const float* bias  = (const float*)d_in[3];
    const int*   nbrs  = (const int*)d_in[4];
    float4* out4 = (float4*)d_out;
    float4* xT4  = (float4*)d_ws;     // needs NN*BT*16 B = 15.36 MB of ws

    dim3 g1((NN + K1_NB - 1) / K1_NB, BT / K1_BT);   // (79, 8)
    hipLaunchKernelGGL(transpose_concat_kernel, g1, dim3(256), 0, stream,
                       (const float4*)x, xT4, out4);

    hipLaunchKernelGGL(gnn_main_kernel, dim3(NN / NPB), dim3(768), 0, stream,
                       (const float4*)xT4, dists, W, bias, nbrs, out4);
}

// Round 3
// 104.833 us; speedup vs baseline: 2.8808x; 2.0816x over previous
//
#include <hip/hip_runtime.h>

// Problem constants
#define Bz 16      // batch
#define Tin 12     // T_IN
#define Ttot 24    // T_TOTAL
#define NN 5000    // nodes
#define Cc 4       // channels
#define KK 16      // neighbors
#define HH 4       // heads
#define OO 12      // T_TOTAL - T_IN
#define TH 48      // Tin * HH
#define BT 192     // Bz * Tin
#define G  8       // bt-groups (2 batches each) == number of XCDs
#define JJ 24      // (b,t) pairs per group

// ============ kernel 1: transpose x -> xT2(g, N, 24) + concat copy ==========
// x is (B,T,N,C) = (BT, N) float4 rows. Group g covers bt in [g*24, g*24+24).
#define K1_NB 64   // nodes per tile
#define K1_BT 24   // (b,t) pairs per tile == JJ (one group per tile row)

__global__ __launch_bounds__(256) void transpose_concat_kernel(
    const float4* __restrict__ x4,   // (BT, N)
    float4* __restrict__ xT2,        // (G, N, JJ)
    float4* __restrict__ out4)       // (B*Ttot, N)
{
    __shared__ float4 tile[K1_BT][K1_NB + 1];
    const int n0  = blockIdx.x * K1_NB;
    const int g   = blockIdx.y;           // group == bt-tile
    const int bt0 = g * K1_BT;
    const int rem = min(K1_NB, NN - n0);
    const int tid = threadIdx.x;

    // load (coalesced along n) + concat copy out[b,t,n,:] = x[b,t,n,:]
    #pragma unroll
    for (int r = 0; r < (K1_NB * K1_BT) / 256; r++) {
        int tau = r * 256 + tid;
        int j = tau / K1_NB;              // bt within tile
        int i = tau % K1_NB;              // node (lane-consecutive)
        if (i < rem) {
            int bt = bt0 + j;
            float4 v = x4[(size_t)bt * NN + n0 + i];
            tile[j][i] = v;
            int b = bt / Tin, t = bt - b * Tin;
            out4[(size_t)(b * Ttot + t) * NN + n0 + i] = v;
        }
    }
    __syncthreads();

    // store xT2: per node 24 float4 = 384 B contiguous; lanes fully contiguous
    #pragma unroll
    for (int r = 0; r < (K1_NB * K1_BT) / 256; r++) {
        int tau = r * 256 + tid;
        int i = tau / K1_BT;              // node
        int j = tau - i * K1_BT;          // j within group (lane-consecutive)
        if (i < rem) {
            xT2[((size_t)g * NN + (n0 + i)) * JJ + j] = tile[j][i];
        }
    }
}

// ============ kernel 2: per-(g, node-block) gather + aggregate + GEMM =======
// grid.x = 625*8; g = blockIdx.x % 8  -> XCD-pinned (dispatch round-robin),
// so group g's 1.92 MB xT2-slice stays resident in XCD g's L2.
#define NPB 8                  // nodes per block (5000 = 625 * 8, exact)
// feat LDS strides (float4 units), padded to break bank alignment:
#define FST 5                  // per-t   (4 heads + 1 pad)
#define FSB 61                 // per-b_l (12*5 + 1)
#define FSN 123                // per-nl  (2*61 + 1)

__global__ __launch_bounds__(192) void gnn_main_kernel(
    const float4* __restrict__ xT2,   // (G, N, JJ)
    const float* __restrict__ dists,  // (N, K)
    const float* __restrict__ W,      // (48, 12)
    const float* __restrict__ bias,   // (12,)
    const int*   __restrict__ nbrs,   // (N, K)
    float4* __restrict__ out4)        // (B*Ttot, N)
{
    __shared__ float4 feat[NPB * FSN];      // 15.7 KB
    __shared__ float4 w4_s[NPB][KK];        // gaussian weights, [nl][k] = 4 heads
    __shared__ float  W_s[TH * OO];
    __shared__ float  bias_s[OO];
    __shared__ int    nbr_s[NPB][KK];

    const int bid = blockIdx.x;
    const int g   = bid & 7;                 // XCD-pin heuristic (locality only)
    const int n0  = (bid >> 3) * NPB;
    const int tid = threadIdx.x;

    // ---- stage small tensors ----
    for (int i = tid; i < TH * OO; i += 192) W_s[i] = W[i];
    if (tid < OO) bias_s[tid] = bias[tid];
    if (tid < NPB * KK) {
        int nl = tid >> 4, k = tid & 15;
        nbr_s[nl][k] = nbrs[(n0 + nl) * KK + k];
        float d = dists[(n0 + nl) * KK + k];
        float e = -(d * d) * (1.0f / 144.0f);   // exponent for h=0 (lam=1/4)
        float4 wv;
        wv.x = expf(e);
        wv.y = expf(2.0f * e);
        wv.z = expf(3.0f * e);
        wv.w = expf(4.0f * e);
        w4_s[nl][k] = wv;
    }
    __syncthreads();

    // ---- phase A: gather (384 B contiguous per neighbor row) + aggregate ----
    {
        const int nl  = tid / JJ;            // 0..7
        const int j   = tid - nl * JJ;       // 0..23 (lane-consecutive)
        const int b_l = j / Tin;             // 0..1
        const int t   = j - b_l * Tin;       // 0..11
        const float4* xg = xT2 + (size_t)g * NN * JJ;

        float4 a0 = {0,0,0,0}, a1 = {0,0,0,0}, a2 = {0,0,0,0}, a3 = {0,0,0,0};
        #pragma unroll
        for (int k = 0; k < KK; k++) {
            float4 xv = xg[(size_t)nbr_s[nl][k] * JJ + j];
            float4 wv = w4_s[nl][k];
            a0.x += wv.x * xv.x; a0.y += wv.x * xv.y; a0.z += wv.x * xv.z; a0.w += wv.x * xv.w;
            a1.x += wv.y * xv.x; a1.y += wv.y * xv.y; a1.z += wv.y * xv.z; a1.w += wv.y * xv.w;
            a2.x += wv.z * xv.x; a2.y += wv.z * xv.y; a2.z += wv.z * xv.z; a2.w += wv.z * xv.w;
            a3.x += wv.w * xv.x; a3.y += wv.w * xv.y; a3.z += wv.w * xv.z; a3.w += wv.w * xv.w;
        }
        const int base = nl * FSN + b_l * FSB + t * FST;
        feat[base + 0] = a0;
        feat[base + 1] = a1;
        feat[base + 2] = a2;
        feat[base + 3] = a3;
    }
    __syncthreads();

    // ---- phase B: (48 -> 12) GEMM + bias + ReLU; 128 B full-line stores ----
    {
        const int nl  = tid & 7;             // lane-consecutive -> 1 full line
        const int bo  = tid >> 3;            // 0..23
        const int b_l = bo / OO;             // 0..1
        const int o   = bo - b_l * OO;       // 0..11
        const float bz = bias_s[o];
        float4 acc = {bz, bz, bz, bz};
        const int fbase = nl * FSN + b_l * FSB;
        #pragma unroll
        for (int t = 0; t < Tin; t++) {
            #pragma unroll
            for (int h = 0; h < HH; h++) {
                float  wv = W_s[(t * HH + h) * OO + o];
                float4 f  = feat[fbase + t * FST + h];
                acc.x += wv * f.x; acc.y += wv * f.y;
                acc.z += wv * f.z; acc.w += wv * f.w;
            }
        }
        acc.x = fmaxf(acc.x, 0.0f); acc.y = fmaxf(acc.y, 0.0f);
        acc.z = fmaxf(acc.z, 0.0f); acc.w = fmaxf(acc.w, 0.0f);
        const int b = g * 2 + b_l;
        out4[(size_t)(b * Ttot + Tin + o) * NN + n0 + nl] = acc;
    }
}

extern "C" void kernel_launch(void* const* d_in, const int* in_sizes, int n_in,
                              void* d_out, int out_size, void* d_ws, size_t ws_size,
                              hipStream_t stream) {
    const float* x     = (const float*)d_in[0];
    const float* dists = (const float*)d_in[1];
    const float* W     = (const float*)d_in[2];
    const float* bias  = (const float*)d_in[3];
    const int*   nbrs  = (const int*)d_in[4];
    float4* out4 = (float4*)d_out;
    float4* xT2  = (float4*)d_ws;     // G*NN*JJ*16 B = 15.36 MB of ws

    dim3 g1((NN + K1_NB - 1) / K1_NB, G);          // (79, 8)
    hipLaunchKernelGGL(transpose_concat_kernel, g1, dim3(256), 0, stream,
                       (const float4*)x, xT2, out4);

    hipLaunchKernelGGL(gnn_main_kernel, dim3((NN / NPB) * G), dim3(192), 0, stream,
                       (const float4*)xT2, dists, W, bias, nbrs, out4);
}